// Round 1
// baseline (198.842 us; speedup 1.0000x reference)
//
#include <hip/hip_runtime.h>
#include <hip/hip_bf16.h>

// Linear attention (BaseMultiHeadAttention_21105469292684)
// M=16, N=2048, C=512, H=8, D=64.  Pipeline:
//   K0: weights fp32 -> bf16 transposed  WT[col][k]
//   K1: Q/K/V = softmax-ish(x @ W) per head, bf16 out   (fused GEMM+softmax)
//   K2: kv partials[mh][ns][64][64] = K_h^T V_h over n-chunks (fp32)
//   K3: WfusedT[m][c][r] = sum_e kv[m,h,d,e] * Wo[h*64+e][c]  (bf16)
//   K4: out[m,n,c] = Q[m,n,:] @ Wfused[m] + bo  (fp32 out)

typedef __bf16 bf16;
typedef __bf16 bf16x8 __attribute__((ext_vector_type(8)));
typedef __bf16 bf16x4 __attribute__((ext_vector_type(4)));
typedef float  f32x4  __attribute__((ext_vector_type(4)));

#define MFMA16(a, b, c) __builtin_amdgcn_mfma_f32_16x16x32_bf16((a), (b), (c), 0, 0, 0)

// ---------------- K0: transpose + convert weights (512x512 each) ----------------
__global__ __launch_bounds__(256) void k_prep(const float* __restrict__ w0, const float* __restrict__ w1,
                                              const float* __restrict__ w2, const float* __restrict__ w3,
                                              bf16* __restrict__ t0, bf16* __restrict__ t1,
                                              bf16* __restrict__ t2, bf16* __restrict__ t3)
{
  const float* W = (blockIdx.z == 0) ? w0 : (blockIdx.z == 1) ? w1 : (blockIdx.z == 2) ? w2 : w3;
  bf16*        T = (blockIdx.z == 0) ? t0 : (blockIdx.z == 1) ? t1 : (blockIdx.z == 2) ? t2 : t3;
  __shared__ float lds[64][68];                 // 68: 16B-aligned stride
  const int t = threadIdx.x;
  const int r = t >> 2, c0 = (t & 3) << 4;      // r:0..63, c0:{0,16,32,48}
  const float* src = W + (size_t)(blockIdx.x * 64 + r) * 512 + blockIdx.y * 64 + c0;
  float4 f0 = ((const float4*)src)[0];
  float4 f1 = ((const float4*)src)[1];
  float4 f2 = ((const float4*)src)[2];
  float4 f3 = ((const float4*)src)[3];
  *(float4*)&lds[r][c0 + 0]  = f0;
  *(float4*)&lds[r][c0 + 4]  = f1;
  *(float4*)&lds[r][c0 + 8]  = f2;
  *(float4*)&lds[r][c0 + 12] = f3;
  __syncthreads();
  bf16 v[16];
#pragma unroll
  for (int s = 0; s < 16; ++s) v[s] = (bf16)lds[c0 + s][r];
  bf16* dst = T + (size_t)(blockIdx.y * 64 + r) * 512 + blockIdx.x * 64 + c0;
  *(bf16x8*)&dst[0] = *(bf16x8*)&v[0];
  *(bf16x8*)&dst[8] = *(bf16x8*)&v[8];
}

// ---------------- K1: fused projection + per-head softmax ----------------
// grid (512, 1, 3): 512 row-blocks of 64 rows, z = proj (0:Q,1:K,2:V). 512 thr = 8 waves.
// BM=64, BN=512 (full width, wave w owns head w), BK=32.
__global__ __launch_bounds__(512) void k_qkv(const float* __restrict__ xq, const float* __restrict__ xk,
                                             const float* __restrict__ xv,
                                             const bf16* __restrict__ WqT, const bf16* __restrict__ WkT,
                                             const bf16* __restrict__ WvT,
                                             bf16* __restrict__ Qo, bf16* __restrict__ Ko, bf16* __restrict__ Vo)
{
  const int proj = blockIdx.z;
  const float* X  = (proj == 0) ? xq  : (proj == 1) ? xk  : xv;
  const bf16*  WT = (proj == 0) ? WqT : (proj == 1) ? WkT : WvT;
  bf16*       OUT = (proj == 0) ? Qo  : (proj == 1) ? Ko  : Vo;

  __shared__ bf16 As[64][40];    // 40-elem (80 B) stride: 16B-aligned, 2-way banks only
  __shared__ bf16 Bs[512][40];

  const int t = threadIdx.x;
  const int lane = t & 63, wave = t >> 6;      // wave = head
  const int g = lane >> 4, li = lane & 15;
  const size_t arow = (size_t)blockIdx.x * 64;

  f32x4 acc[4][4] = {};

  const int ar = t >> 3, ac = (t & 7) << 2;    // A staging: 64 rows x 8 float4
  const int br = t >> 2, bc = (t & 3) << 3;    // B staging: 4 x (128 rows x 4 bf16x8)

  for (int kt = 0; kt < 16; ++kt) {
    const int k0 = kt * 32;
    __syncthreads();
    {  // stage A (fp32 -> bf16), fully coalesced float4 loads
      float4 f = *(const float4*)(X + (arow + ar) * 512 + k0 + ac);
      bf16x4 h; h[0] = (bf16)f.x; h[1] = (bf16)f.y; h[2] = (bf16)f.z; h[3] = (bf16)f.w;
      *(bf16x4*)&As[ar][ac] = h;
    }
#pragma unroll
    for (int i = 0; i < 4; ++i) {  // stage B (WT rows = out-cols, k-contiguous)
      const int r = br + i * 128;
      bf16x8 b = *(const bf16x8*)(WT + (size_t)r * 512 + k0 + bc);
      *(bf16x8*)&Bs[r][bc] = b;
    }
    __syncthreads();
    bf16x8 af[4], bfr[4];
#pragma unroll
    for (int rt = 0; rt < 4; ++rt) af[rt]  = *(const bf16x8*)&As[rt * 16 + li][g * 8];
#pragma unroll
    for (int ct = 0; ct < 4; ++ct) bfr[ct] = *(const bf16x8*)&Bs[wave * 64 + ct * 16 + li][g * 8];
#pragma unroll
    for (int rt = 0; rt < 4; ++rt)
#pragma unroll
      for (int ct = 0; ct < 4; ++ct)
        acc[rt][ct] = MFMA16(af[rt], bfr[ct], acc[rt][ct]);
  }

  // epilogue: softmax over the 64 head columns (rows are (g*4+q | rt); cols ct*16+li)
#pragma unroll
  for (int rt = 0; rt < 4; ++rt) {
#pragma unroll
    for (int q = 0; q < 4; ++q) {
      float v0 = acc[rt][0][q], v1 = acc[rt][1][q], v2 = acc[rt][2][q], v3 = acc[rt][3][q];
      if (proj < 2) {
        float mx = fmaxf(fmaxf(v0, v1), fmaxf(v2, v3));
        mx = fmaxf(mx, __shfl_xor(mx, 1));
        mx = fmaxf(mx, __shfl_xor(mx, 2));
        mx = fmaxf(mx, __shfl_xor(mx, 4));
        mx = fmaxf(mx, __shfl_xor(mx, 8));
        v0 = __expf(v0 - mx); v1 = __expf(v1 - mx); v2 = __expf(v2 - mx); v3 = __expf(v3 - mx);
        float s = v0 + v1 + v2 + v3;
        s += __shfl_xor(s, 1); s += __shfl_xor(s, 2); s += __shfl_xor(s, 4); s += __shfl_xor(s, 8);
        const float inv = (proj == 0 ? 0.125f : 1.0f) / s;   // q gets *D^-0.5
        v0 *= inv; v1 *= inv; v2 *= inv; v3 *= inv;
      }
      bf16* o = OUT + (arow + rt * 16 + g * 4 + q) * 512 + wave * 64 + li;
      o[0] = (bf16)v0; o[16] = (bf16)v1; o[32] = (bf16)v2; o[48] = (bf16)v3;
    }
  }
}

// ---------------- K2: kv partials = K_h^T V_h over an n-chunk ----------------
// grid (128, 4): x = m*8+h, y = n-chunk (512 rows). 256 thr = 4 waves (2x2 quadrants of 64x64).
__global__ __launch_bounds__(256) void k_kv(const bf16* __restrict__ K, const bf16* __restrict__ V,
                                            float* __restrict__ kvp)
{
  const int mh = blockIdx.x, m = mh >> 3, h = mh & 7;
  const int ns = blockIdx.y;
  __shared__ bf16 Kt[64][40];  // [d][n-within-32], transposed staging
  __shared__ bf16 Vt[64][40];
  const int t = threadIdx.x, lane = t & 63, wave = t >> 6;
  const int dq = wave >> 1, eq = wave & 1;
  const int g = lane >> 4, li = lane & 15;
  const int tn = t & 31, d0 = (t >> 5) << 3;
  const size_t rowbase = (size_t)m * 2048 + ns * 512;

  f32x4 acc[2][2] = {};

  for (int nt = 0; nt < 16; ++nt) {
    __syncthreads();
    {
      bf16x8 kr = *(const bf16x8*)(K + (rowbase + nt * 32 + tn) * 512 + h * 64 + d0);
      bf16x8 vr = *(const bf16x8*)(V + (rowbase + nt * 32 + tn) * 512 + h * 64 + d0);
#pragma unroll
      for (int j = 0; j < 8; ++j) Kt[d0 + j][tn] = kr[j];
#pragma unroll
      for (int j = 0; j < 8; ++j) Vt[d0 + j][tn] = vr[j];
    }
    __syncthreads();
    bf16x8 af[2], bfr[2];
#pragma unroll
    for (int dt = 0; dt < 2; ++dt) af[dt]  = *(const bf16x8*)&Kt[dq * 32 + dt * 16 + li][g * 8];
#pragma unroll
    for (int et = 0; et < 2; ++et) bfr[et] = *(const bf16x8*)&Vt[eq * 32 + et * 16 + li][g * 8];
#pragma unroll
    for (int dt = 0; dt < 2; ++dt)
#pragma unroll
      for (int et = 0; et < 2; ++et)
        acc[dt][et] = MFMA16(af[dt], bfr[et], acc[dt][et]);
  }

  float* o = kvp + ((size_t)mh * 4 + ns) * 4096;
#pragma unroll
  for (int dt = 0; dt < 2; ++dt)
#pragma unroll
    for (int et = 0; et < 2; ++et)
#pragma unroll
      for (int q = 0; q < 4; ++q) {
        const int d = dq * 32 + dt * 16 + g * 4 + q;
        const int e = eq * 32 + et * 16 + li;
        o[d * 64 + e] = acc[dt][et][q];
      }
}

// ---------------- K3: WfusedT[m][c][r=h*64+d] = sum_e kv[d][e] * WoT[c][h*64+e] ----------------
// grid (128): x = m*8+h. 512 thr = 8 waves; wave owns 64 c-rows, all 64 d-cols. K=64.
__global__ __launch_bounds__(512) void k_wfused(const float* __restrict__ kvp, const bf16* __restrict__ WoT,
                                                bf16* __restrict__ WfT)
{
  const int mh = blockIdx.x, m = mh >> 3, h = mh & 7;
  __shared__ bf16 kvs[64][72];   // [d][e], 144 B stride
  const int t = threadIdx.x, lane = t & 63, wave = t >> 6;
  const int g = lane >> 4, li = lane & 15;
  {
    const int d = t >> 3, e0 = (t & 7) << 3;
    const float* p = kvp + (size_t)mh * 16384 + d * 64 + e0;
#pragma unroll
    for (int j = 0; j < 8; ++j) {
      float s = p[j] + p[4096 + j] + p[8192 + j] + p[12288 + j];  // reduce 4 n-chunk partials
      kvs[d][e0 + j] = (bf16)s;
    }
  }
  __syncthreads();
  f32x4 acc[4][4] = {};
#pragma unroll
  for (int kk = 0; kk < 2; ++kk) {
    bf16x8 af[4], bfr[4];
#pragma unroll
    for (int rt = 0; rt < 4; ++rt) {
      const int c = wave * 64 + rt * 16 + li;
      af[rt] = *(const bf16x8*)(WoT + (size_t)c * 512 + h * 64 + kk * 32 + g * 8);
    }
#pragma unroll
    for (int ct = 0; ct < 4; ++ct)
      bfr[ct] = *(const bf16x8*)&kvs[ct * 16 + li][kk * 32 + g * 8];
#pragma unroll
    for (int rt = 0; rt < 4; ++rt)
#pragma unroll
      for (int ct = 0; ct < 4; ++ct)
        acc[rt][ct] = MFMA16(af[rt], bfr[ct], acc[rt][ct]);
  }
  bf16* o = WfT + (size_t)m * 262144;
#pragma unroll
  for (int rt = 0; rt < 4; ++rt)
#pragma unroll
    for (int ct = 0; ct < 4; ++ct)
#pragma unroll
      for (int q = 0; q < 4; ++q) {
        const int c = wave * 64 + rt * 16 + g * 4 + q;
        const int r = h * 64 + ct * 16 + li;
        o[(size_t)c * 512 + r] = (bf16)acc[rt][ct][q];
      }
}

// ---------------- K4: out = Q @ Wfused[m] + bo (fp32 out) ----------------
// grid (512): 64-row blocks (32 per m). 512 thr = 8 waves; wave w owns cols [w*64, w*64+64). BK=32.
__global__ __launch_bounds__(512) void k_out(const bf16* __restrict__ Q, const bf16* __restrict__ WfT,
                                             const float* __restrict__ bo, float* __restrict__ out)
{
  __shared__ bf16 As[64][40];
  __shared__ bf16 Bs[512][40];
  const int rb = blockIdx.x;
  const int m = rb >> 5;                      // 32 row-blocks per m
  const bf16* B = WfT + (size_t)m * 262144;   // WfusedT[m][c][r], r contiguous
  const int t = threadIdx.x, lane = t & 63, wave = t >> 6;
  const int g = lane >> 4, li = lane & 15;
  const size_t arow = (size_t)rb * 64;

  f32x4 acc[4][4] = {};
  const int ar = t >> 3, ac = (t & 7) << 2;   // A: 64 rows x 8 bf16x4
  const int br = t >> 2, bc = (t & 3) << 3;

  for (int kt = 0; kt < 16; ++kt) {
    const int k0 = kt * 32;
    __syncthreads();
    {
      bf16x4 a = *(const bf16x4*)(Q + (arow + ar) * 512 + k0 + ac);
      *(bf16x4*)&As[ar][ac] = a;
    }
#pragma unroll
    for (int i = 0; i < 4; ++i) {
      const int r = br + i * 128;
      bf16x8 b = *(const bf16x8*)(B + (size_t)r * 512 + k0 + bc);
      *(bf16x8*)&Bs[r][bc] = b;
    }
    __syncthreads();
    bf16x8 af[4], bfr[4];
#pragma unroll
    for (int rt = 0; rt < 4; ++rt) af[rt]  = *(const bf16x8*)&As[rt * 16 + li][g * 8];
#pragma unroll
    for (int ct = 0; ct < 4; ++ct) bfr[ct] = *(const bf16x8*)&Bs[wave * 64 + ct * 16 + li][g * 8];
#pragma unroll
    for (int rt = 0; rt < 4; ++rt)
#pragma unroll
      for (int ct = 0; ct < 4; ++ct)
        acc[rt][ct] = MFMA16(af[rt], bfr[ct], acc[rt][ct]);
  }

  float bv[4];
#pragma unroll
  for (int ct = 0; ct < 4; ++ct) bv[ct] = bo[wave * 64 + ct * 16 + li];
#pragma unroll
  for (int rt = 0; rt < 4; ++rt)
#pragma unroll
    for (int q = 0; q < 4; ++q) {
      float* o = out + (arow + rt * 16 + g * 4 + q) * 512 + wave * 64 + li;
      o[0]  = acc[rt][0][q] + bv[0];
      o[16] = acc[rt][1][q] + bv[1];
      o[32] = acc[rt][2][q] + bv[2];
      o[48] = acc[rt][3][q] + bv[3];
    }
}

// ---------------- host ----------------
extern "C" void kernel_launch(void* const* d_in, const int* in_sizes, int n_in,
                              void* d_out, int out_size, void* d_ws, size_t ws_size,
                              hipStream_t stream)
{
  const float* xq = (const float*)d_in[0];
  const float* xk = (const float*)d_in[1];
  const float* xv = (const float*)d_in[2];
  const float* Wq = (const float*)d_in[3];
  const float* Wk = (const float*)d_in[4];
  const float* Wv = (const float*)d_in[5];
  const float* Wo = (const float*)d_in[6];
  const float* bo = (const float*)d_in[7];
  float* out = (float*)d_out;

  char* ws = (char*)d_ws;
  const size_t WT_BYTES  = 512 * 512 * 2;           // 512 KiB each
  const size_t QKV_BYTES = (size_t)32768 * 512 * 2; // 32 MiB each
  bf16*  WqT = (bf16*)(ws);
  bf16*  WkT = (bf16*)(ws + WT_BYTES);
  bf16*  WvT = (bf16*)(ws + 2 * WT_BYTES);
  bf16*  WoT = (bf16*)(ws + 3 * WT_BYTES);
  bf16*  Qb  = (bf16*)(ws + 4 * WT_BYTES);
  bf16*  Kb  = (bf16*)(ws + 4 * WT_BYTES + QKV_BYTES);
  bf16*  Vb  = (bf16*)(ws + 4 * WT_BYTES + 2 * QKV_BYTES);
  float* kvp = (float*)(ws + 4 * WT_BYTES + 3 * QKV_BYTES);  // 128*4*4096*4 = 8 MiB
  bf16*  WfT = Kb;  // overlay: Kb is dead after k_kv; total ws use ~106 MiB

  k_prep  <<<dim3(8, 8, 4),   256, 0, stream>>>(Wq, Wk, Wv, Wo, WqT, WkT, WvT, WoT);
  k_qkv   <<<dim3(512, 1, 3), 512, 0, stream>>>(xq, xk, xv, WqT, WkT, WvT, Qb, Kb, Vb);
  k_kv    <<<dim3(128, 4),    256, 0, stream>>>(Kb, Vb, kvp);
  k_wfused<<<dim3(128),       512, 0, stream>>>(kvp, WoT, WfT);
  k_out   <<<dim3(512),       512, 0, stream>>>(Qb, WfT, bo, out);
}

// Round 2
// 178.161 us; speedup vs baseline: 1.1161x; 1.1161x over previous
//
#include <hip/hip_runtime.h>
#include <hip/hip_bf16.h>

// Linear attention (BaseMultiHeadAttention_21105469292684)
// M=16, N=2048, C=512, H=8, D=64.
//   K0a: proj weights fp32 -> bf16 in MFMA-fragment-major layout
//   K0b: Wo fp32 -> bf16 transposed WoT[c][k]
//   K1 : Q/K/V = softmax-ish(x @ W) per head, bf16 out (BM=128, BN=512, reg-B)
//   K2 : kv partials = K_h^T V_h over n-chunks (fp32)
//   K3 : WfusedT[m][c][r] = sum_e kv[m,h,d,e] * Wo[h*64+e][c]  (bf16)
//   K4 : out[m,n,c] = Q[m,n,:] @ Wfused[m] + bo  (fp32 out)

typedef __bf16 bf16;
typedef __bf16 bf16x8 __attribute__((ext_vector_type(8)));
typedef __bf16 bf16x4 __attribute__((ext_vector_type(4)));
typedef float  f32x4  __attribute__((ext_vector_type(4)));

#define MFMA16(a, b, c) __builtin_amdgcn_mfma_f32_16x16x32_bf16((a), (b), (c), 0, 0, 0)

__device__ inline bf16x8 cvt8(float4 a, float4 b) {
  bf16x8 h;
  h[0] = (bf16)a.x; h[1] = (bf16)a.y; h[2] = (bf16)a.z; h[3] = (bf16)a.w;
  h[4] = (bf16)b.x; h[5] = (bf16)b.y; h[6] = (bf16)b.z; h[7] = (bf16)b.w;
  return h;
}

// ---------------- K0a: proj weights -> fragment-major bf16 ----------------
// Layout (elements): [cg 4][kt 8][ksub 2][cb7 8][lane 64][8]
//   element W[k][c]: cg=c>>7, kt=k>>6, ksub=(k>>5)&1, cb7=(c>>4)&7,
//                    lane=((k>>3)&3)*16 + (c&15), last = k&7
__global__ __launch_bounds__(256) void k_prep_frag(const float* __restrict__ w0, const float* __restrict__ w1,
                                                   const float* __restrict__ w2,
                                                   bf16* __restrict__ f0, bf16* __restrict__ f1,
                                                   bf16* __restrict__ f2)
{
  const float* W = (blockIdx.z == 0) ? w0 : (blockIdx.z == 1) ? w1 : w2;
  bf16*        F = (blockIdx.z == 0) ? f0 : (blockIdx.z == 1) ? f1 : f2;
  __shared__ float lds[64][68];
  const int t = threadIdx.x;
  const int bx = blockIdx.x, by = blockIdx.y;   // bx: k-tile(64), by: c-tile(64)
  {
    const int r = t >> 2, c0 = (t & 3) << 4;
    const float* src = W + (size_t)(bx * 64 + r) * 512 + by * 64 + c0;
    float4 a = ((const float4*)src)[0], b = ((const float4*)src)[1];
    float4 c = ((const float4*)src)[2], d = ((const float4*)src)[3];
    *(float4*)&lds[r][c0 + 0]  = a; *(float4*)&lds[r][c0 + 4]  = b;
    *(float4*)&lds[r][c0 + 8]  = c; *(float4*)&lds[r][c0 + 12] = d;
  }
  __syncthreads();
#pragma unroll
  for (int it = 0; it < 2; ++it) {
    const int ch = t + it * 256;
    const int kc = ch >> 6, cc = ch & 63;       // k-octet, c within tile
    bf16x8 v;
#pragma unroll
    for (int j = 0; j < 8; ++j) v[j] = (bf16)lds[kc * 8 + j][cc];
    const int cg   = by >> 1;
    const int cb7  = ((by & 1) << 2) | (cc >> 4);
    const int ksub = kc >> 2, g = kc & 3, li = cc & 15;
    const size_t off = (size_t)cg * 65536 + (size_t)bx * 8192 + ksub * 4096 + cb7 * 512 + (g * 16 + li) * 8;
    *(bf16x8*)(F + off) = v;
  }
}

// ---------------- K0b: Wo -> plain transposed bf16 WoT[c][k] ----------------
__global__ __launch_bounds__(256) void k_prep_wo(const float* __restrict__ W, bf16* __restrict__ T)
{
  __shared__ float lds[64][68];
  const int t = threadIdx.x;
  const int r = t >> 2, c0 = (t & 3) << 4;
  const float* src = W + (size_t)(blockIdx.x * 64 + r) * 512 + blockIdx.y * 64 + c0;
  float4 f0 = ((const float4*)src)[0];
  float4 f1 = ((const float4*)src)[1];
  float4 f2 = ((const float4*)src)[2];
  float4 f3 = ((const float4*)src)[3];
  *(float4*)&lds[r][c0 + 0]  = f0;
  *(float4*)&lds[r][c0 + 4]  = f1;
  *(float4*)&lds[r][c0 + 8]  = f2;
  *(float4*)&lds[r][c0 + 12] = f3;
  __syncthreads();
  bf16 v[16];
#pragma unroll
  for (int s = 0; s < 16; ++s) v[s] = (bf16)lds[c0 + s][r];
  bf16* dst = T + (size_t)(blockIdx.y * 64 + r) * 512 + blockIdx.x * 64 + c0;
  *(bf16x8*)&dst[0] = *(bf16x8*)&v[0];
  *(bf16x8*)&dst[8] = *(bf16x8*)&v[8];
}

// ---------------- K1: fused projection + per-head softmax ----------------
// grid (256,1,3): 256 blocks of 128 rows, z = proj. 512 thr = 8 waves.
// BM=128, BN=512, BK=64. Wave w owns head w: 128 rows x 64 cols (acc[8][4]).
// A: LDS double-buffered (pad 72, conflict-free). B: fragment-major global -> regs.
__global__ __launch_bounds__(512, 2) void k_qkv(const float* __restrict__ xq, const float* __restrict__ xk,
                                                const float* __restrict__ xv,
                                                const bf16* __restrict__ Fq, const bf16* __restrict__ Fk,
                                                const bf16* __restrict__ Fv,
                                                bf16* __restrict__ Qo, bf16* __restrict__ Ko,
                                                bf16* __restrict__ Vo)
{
  const int proj = blockIdx.z;
  const float* X  = (proj == 0) ? xq : (proj == 1) ? xk : xv;
  const bf16*  F  = (proj == 0) ? Fq : (proj == 1) ? Fk : Fv;
  bf16*       OUT = (proj == 0) ? Qo : (proj == 1) ? Ko : Vo;

  __shared__ bf16 As[2][128][72];   // 36.9 KB

  const int t = threadIdx.x, lane = t & 63, w = t >> 6;   // w = head
  const int g = lane >> 4, li = lane & 15;
  const size_t arow = (size_t)blockIdx.x * 128;

  // per-wave fragment base: head w -> cg=w>>1, cb7 base=(w&1)*4
  const bf16* Fw = F + (w >> 1) * 65536 + (w & 1) * 2048 + lane * 8;

  const int sr = t >> 2, sc = (t & 3) << 4;               // A staging: 128 rows x 4x16 cols
  const float* xp0 = X + (arow + sr) * 512 + sc;

  f32x4 acc[8][4] = {};

  // prologue: stage A for kt=0; preload B frags for hs=0
  {
    float4 xa[4];
#pragma unroll
    for (int i = 0; i < 4; ++i) xa[i] = ((const float4*)xp0)[i];
    *(bf16x8*)&As[0][sr][sc]     = cvt8(xa[0], xa[1]);
    *(bf16x8*)&As[0][sr][sc + 8] = cvt8(xa[2], xa[3]);
  }
  bf16x8 bfc[4];
#pragma unroll
  for (int ct = 0; ct < 4; ++ct) bfc[ct] = *(const bf16x8*)(Fw + ct * 512);
  __syncthreads();

  float4 xa[4];
  // 16 half-steps: hs = kt*2 + ksub, BK=64 per kt
#pragma unroll
  for (int hs = 0; hs < 16; ++hs) {
    const int kt = hs >> 1, cur = kt & 1;
    bf16x8 bfn[4];
    if (hs < 15) {   // prefetch next half-step's B frags (L2-hot, coalesced 1KB/instr)
      const bf16* p = Fw + ((hs + 1) >> 1) * 8192 + ((hs + 1) & 1) * 4096;
#pragma unroll
      for (int ct = 0; ct < 4; ++ct) bfn[ct] = *(const bf16x8*)(p + ct * 512);
    }
    if ((hs & 1) == 0 && kt < 7) {  // early-issue next A-tile global loads (T14)
#pragma unroll
      for (int i = 0; i < 4; ++i) xa[i] = ((const float4*)(xp0 + (kt + 1) * 64))[i];
    }
    // compute this half-step
    {
      bf16x8 af[8];
#pragma unroll
      for (int rt = 0; rt < 8; ++rt)
        af[rt] = *(const bf16x8*)&As[cur][rt * 16 + li][(hs & 1) * 32 + g * 8];
#pragma unroll
      for (int rt = 0; rt < 8; ++rt)
#pragma unroll
        for (int ct = 0; ct < 4; ++ct)
          acc[rt][ct] = MFMA16(af[rt], bfc[ct], acc[rt][ct]);
    }
    if (hs & 1) {                   // end of kt: write next A buffer, barrier
      if (kt < 7) {
        *(bf16x8*)&As[cur ^ 1][sr][sc]     = cvt8(xa[0], xa[1]);
        *(bf16x8*)&As[cur ^ 1][sr][sc + 8] = cvt8(xa[2], xa[3]);
      }
      if (hs < 15) __syncthreads();
    }
    if (hs < 15) {
#pragma unroll
      for (int ct = 0; ct < 4; ++ct) bfc[ct] = bfn[ct];
    }
  }

  // epilogue: per-head softmax over 64 cols (4 ct x 16 li), rows = rt*16+g*4+q
#pragma unroll
  for (int rt = 0; rt < 8; ++rt) {
#pragma unroll
    for (int q = 0; q < 4; ++q) {
      float v0 = acc[rt][0][q], v1 = acc[rt][1][q], v2 = acc[rt][2][q], v3 = acc[rt][3][q];
      if (proj < 2) {
        float mx = fmaxf(fmaxf(v0, v1), fmaxf(v2, v3));
        mx = fmaxf(mx, __shfl_xor(mx, 1));
        mx = fmaxf(mx, __shfl_xor(mx, 2));
        mx = fmaxf(mx, __shfl_xor(mx, 4));
        mx = fmaxf(mx, __shfl_xor(mx, 8));
        v0 = __expf(v0 - mx); v1 = __expf(v1 - mx); v2 = __expf(v2 - mx); v3 = __expf(v3 - mx);
        float s = v0 + v1 + v2 + v3;
        s += __shfl_xor(s, 1); s += __shfl_xor(s, 2); s += __shfl_xor(s, 4); s += __shfl_xor(s, 8);
        const float inv = (proj == 0 ? 0.125f : 1.0f) / s;
        v0 *= inv; v1 *= inv; v2 *= inv; v3 *= inv;
      }
      bf16* o = OUT + (arow + rt * 16 + g * 4 + q) * 512 + w * 64 + li;
      o[0] = (bf16)v0; o[16] = (bf16)v1; o[32] = (bf16)v2; o[48] = (bf16)v3;
    }
  }
}

// ---------------- K2: kv partials = K_h^T V_h over an n-chunk ----------------
__global__ __launch_bounds__(256) void k_kv(const bf16* __restrict__ K, const bf16* __restrict__ V,
                                            float* __restrict__ kvp)
{
  const int mh = blockIdx.x, m = mh >> 3, h = mh & 7;
  const int ns = blockIdx.y;
  __shared__ bf16 Kt[64][40];
  __shared__ bf16 Vt[64][40];
  const int t = threadIdx.x, lane = t & 63, wave = t >> 6;
  const int dq = wave >> 1, eq = wave & 1;
  const int g = lane >> 4, li = lane & 15;
  const int tn = t & 31, d0 = (t >> 5) << 3;
  const size_t rowbase = (size_t)m * 2048 + ns * 512;

  f32x4 acc[2][2] = {};

  for (int nt = 0; nt < 16; ++nt) {
    __syncthreads();
    {
      bf16x8 kr = *(const bf16x8*)(K + (rowbase + nt * 32 + tn) * 512 + h * 64 + d0);
      bf16x8 vr = *(const bf16x8*)(V + (rowbase + nt * 32 + tn) * 512 + h * 64 + d0);
#pragma unroll
      for (int j = 0; j < 8; ++j) Kt[d0 + j][tn] = kr[j];
#pragma unroll
      for (int j = 0; j < 8; ++j) Vt[d0 + j][tn] = vr[j];
    }
    __syncthreads();
    bf16x8 af[2], bfr[2];
#pragma unroll
    for (int dt = 0; dt < 2; ++dt) af[dt]  = *(const bf16x8*)&Kt[dq * 32 + dt * 16 + li][g * 8];
#pragma unroll
    for (int et = 0; et < 2; ++et) bfr[et] = *(const bf16x8*)&Vt[eq * 32 + et * 16 + li][g * 8];
#pragma unroll
    for (int dt = 0; dt < 2; ++dt)
#pragma unroll
      for (int et = 0; et < 2; ++et)
        acc[dt][et] = MFMA16(af[dt], bfr[et], acc[dt][et]);
  }

  float* o = kvp + ((size_t)mh * 4 + ns) * 4096;
#pragma unroll
  for (int dt = 0; dt < 2; ++dt)
#pragma unroll
    for (int et = 0; et < 2; ++et)
#pragma unroll
      for (int q = 0; q < 4; ++q) {
        const int d = dq * 32 + dt * 16 + g * 4 + q;
        const int e = eq * 32 + et * 16 + li;
        o[d * 64 + e] = acc[dt][et][q];
      }
}

// ---------------- K3: WfusedT[m][c][r=h*64+d] = sum_e kv[d][e] * WoT[c][h*64+e] ----------------
__global__ __launch_bounds__(512) void k_wfused(const float* __restrict__ kvp, const bf16* __restrict__ WoT,
                                                bf16* __restrict__ WfT)
{
  const int mh = blockIdx.x, m = mh >> 3, h = mh & 7;
  __shared__ bf16 kvs[64][72];
  const int t = threadIdx.x, lane = t & 63, wave = t >> 6;
  const int g = lane >> 4, li = lane & 15;
  {
    const int d = t >> 3, e0 = (t & 7) << 3;
    const float* p = kvp + (size_t)mh * 16384 + d * 64 + e0;
#pragma unroll
    for (int j = 0; j < 8; ++j) {
      float s = p[j] + p[4096 + j] + p[8192 + j] + p[12288 + j];
      kvs[d][e0 + j] = (bf16)s;
    }
  }
  __syncthreads();
  f32x4 acc[4][4] = {};
#pragma unroll
  for (int kk = 0; kk < 2; ++kk) {
    bf16x8 af[4], bfr[4];
#pragma unroll
    for (int rt = 0; rt < 4; ++rt) {
      const int c = wave * 64 + rt * 16 + li;
      af[rt] = *(const bf16x8*)(WoT + (size_t)c * 512 + h * 64 + kk * 32 + g * 8);
    }
#pragma unroll
    for (int ct = 0; ct < 4; ++ct)
      bfr[ct] = *(const bf16x8*)&kvs[ct * 16 + li][kk * 32 + g * 8];
#pragma unroll
    for (int rt = 0; rt < 4; ++rt)
#pragma unroll
      for (int ct = 0; ct < 4; ++ct)
        acc[rt][ct] = MFMA16(af[rt], bfr[ct], acc[rt][ct]);
  }
  bf16* o = WfT + (size_t)m * 262144;
#pragma unroll
  for (int rt = 0; rt < 4; ++rt)
#pragma unroll
    for (int ct = 0; ct < 4; ++ct)
#pragma unroll
      for (int q = 0; q < 4; ++q) {
        const int c = wave * 64 + rt * 16 + g * 4 + q;
        const int r = h * 64 + ct * 16 + li;
        o[(size_t)c * 512 + r] = (bf16)acc[rt][ct][q];
      }
}

// ---------------- K4: out = Q @ Wfused[m] + bo (fp32 out) ----------------
__global__ __launch_bounds__(512) void k_out(const bf16* __restrict__ Q, const bf16* __restrict__ WfT,
                                             const float* __restrict__ bo, float* __restrict__ out)
{
  __shared__ bf16 As2[64][40];
  __shared__ bf16 Bs[512][40];
  const int rb = blockIdx.x;
  const int m = rb >> 5;
  const bf16* B = WfT + (size_t)m * 262144;
  const int t = threadIdx.x, lane = t & 63, wave = t >> 6;
  const int g = lane >> 4, li = lane & 15;
  const size_t arow = (size_t)rb * 64;

  f32x4 acc[4][4] = {};
  const int ar = t >> 3, ac = (t & 7) << 2;
  const int br = t >> 2, bc = (t & 3) << 3;

  for (int kt = 0; kt < 16; ++kt) {
    const int k0 = kt * 32;
    __syncthreads();
    {
      bf16x4 a = *(const bf16x4*)(Q + (arow + ar) * 512 + k0 + ac);
      *(bf16x4*)&As2[ar][ac] = a;
    }
#pragma unroll
    for (int i = 0; i < 4; ++i) {
      const int r = br + i * 128;
      bf16x8 b = *(const bf16x8*)(B + (size_t)r * 512 + k0 + bc);
      *(bf16x8*)&Bs[r][bc] = b;
    }
    __syncthreads();
    bf16x8 af[4], bfr[4];
#pragma unroll
    for (int rt = 0; rt < 4; ++rt) af[rt]  = *(const bf16x8*)&As2[rt * 16 + li][g * 8];
#pragma unroll
    for (int ct = 0; ct < 4; ++ct) bfr[ct] = *(const bf16x8*)&Bs[wave * 64 + ct * 16 + li][g * 8];
#pragma unroll
    for (int rt = 0; rt < 4; ++rt)
#pragma unroll
      for (int ct = 0; ct < 4; ++ct)
        acc[rt][ct] = MFMA16(af[rt], bfr[ct], acc[rt][ct]);
  }

  float bv[4];
#pragma unroll
  for (int ct = 0; ct < 4; ++ct) bv[ct] = bo[wave * 64 + ct * 16 + li];
#pragma unroll
  for (int rt = 0; rt < 4; ++rt)
#pragma unroll
    for (int q = 0; q < 4; ++q) {
      float* o = out + (arow + rt * 16 + g * 4 + q) * 512 + wave * 64 + li;
      o[0]  = acc[rt][0][q] + bv[0];
      o[16] = acc[rt][1][q] + bv[1];
      o[32] = acc[rt][2][q] + bv[2];
      o[48] = acc[rt][3][q] + bv[3];
    }
}

// ---------------- host ----------------
extern "C" void kernel_launch(void* const* d_in, const int* in_sizes, int n_in,
                              void* d_out, int out_size, void* d_ws, size_t ws_size,
                              hipStream_t stream)
{
  const float* xq = (const float*)d_in[0];
  const float* xk = (const float*)d_in[1];
  const float* xv = (const float*)d_in[2];
  const float* Wq = (const float*)d_in[3];
  const float* Wk = (const float*)d_in[4];
  const float* Wv = (const float*)d_in[5];
  const float* Wo = (const float*)d_in[6];
  const float* bo = (const float*)d_in[7];
  float* out = (float*)d_out;

  char* ws = (char*)d_ws;
  const size_t WT_BYTES  = 512 * 512 * 2;
  const size_t QKV_BYTES = (size_t)32768 * 512 * 2;
  bf16*  WFq = (bf16*)(ws);
  bf16*  WFk = (bf16*)(ws + WT_BYTES);
  bf16*  WFv = (bf16*)(ws + 2 * WT_BYTES);
  bf16*  WoT = (bf16*)(ws + 3 * WT_BYTES);
  bf16*  Qb  = (bf16*)(ws + 4 * WT_BYTES);
  bf16*  Kb  = (bf16*)(ws + 4 * WT_BYTES + QKV_BYTES);
  bf16*  Vb  = (bf16*)(ws + 4 * WT_BYTES + 2 * QKV_BYTES);
  float* kvp = (float*)(ws + 4 * WT_BYTES + 3 * QKV_BYTES);
  bf16*  WfT = Kb;  // overlay: Kb dead after k_kv

  k_prep_frag<<<dim3(8, 8, 3), 256, 0, stream>>>(Wq, Wk, Wv, WFq, WFk, WFv);
  k_prep_wo  <<<dim3(8, 8),    256, 0, stream>>>(Wo, WoT);
  k_qkv      <<<dim3(256, 1, 3), 512, 0, stream>>>(xq, xk, xv, WFq, WFk, WFv, Qb, Kb, Vb);
  k_kv       <<<dim3(128, 4),  256, 0, stream>>>(Kb, Vb, kvp);
  k_wfused   <<<dim3(128),     512, 0, stream>>>(kvp, WoT, WfT);
  k_out      <<<dim3(512),     512, 0, stream>>>(Qb, WfT, bo, out);
}